// Round 1
// baseline (142.186 us; speedup 1.0000x reference)
//
#include <hip/hip_runtime.h>

#define NB 16384     // rows (B)
#define NC 1000      // classes (C)
#define NV4 250      // float4 per row = NC/4
#define KPL 4        // float4 per lane (64 lanes * 4 = 256 >= 250)

// One WAVE per row. No LDS, no __syncthreads.
// Each lane: 4 float4 of target + 4 float4 of logits (coalesced, stride 64 float4).
// Argmax reduction carries (target_val, idx, logit_at_idx) so x1 needs no re-read.
__global__ __launch_bounds__(256) void ranking_loss_kernel(
        const float* __restrict__ logits,
        const float* __restrict__ target,
        float* __restrict__ partial) {
    const int wave = threadIdx.x >> 6;
    const int lane = threadIdx.x & 63;
    const int row  = blockIdx.x * 4 + wave;   // grid = NB/4, always in range

    const float4* __restrict__ trow = (const float4*)(target + (size_t)row * NC);
    const float4* __restrict__ lrow = (const float4*)(logits + (size_t)row * NC);

    // ---- issue all global loads up front (8 independent float4 loads) ----
    float4 tv[KPL], lv[KPL];
    #pragma unroll
    for (int k = 0; k < KPL; ++k) {
        const int idx = lane + 64 * k;        // coalesced within each k
        if (idx < NV4) {
            tv[k] = trow[idx];
            lv[k] = lrow[idx];
        } else {                               // only lanes 58..63 at k==3
            tv[k] = make_float4(-INFINITY, -INFINITY, -INFINITY, -INFINITY);
            lv[k] = make_float4(0.f, 0.f, 0.f, 0.f);
        }
    }

    // ---- per-lane argmax(target) scan, tracking the co-located logit ----
    float bv = -INFINITY;   // best target value
    int   bi = NC;          // best (smallest on tie) global index
    float bl = 0.0f;        // logit at best index  -> becomes x1
    #pragma unroll
    for (int k = 0; k < KPL; ++k) {
        const int base = (lane + 64 * k) * 4;
        const float tvals[4] = {tv[k].x, tv[k].y, tv[k].z, tv[k].w};
        const float lvals[4] = {lv[k].x, lv[k].y, lv[k].z, lv[k].w};
        #pragma unroll
        for (int e = 0; e < 4; ++e) {
            const int j = base + e;
            if (tvals[e] > bv || (tvals[e] == bv && j < bi)) {
                bv = tvals[e]; bi = j; bl = lvals[e];
            }
        }
    }

    // ---- wave-level argmax reduction (carries the logit along) ----
    #pragma unroll
    for (int off = 32; off > 0; off >>= 1) {
        const float ov = __shfl_down(bv, off, 64);
        const int   oi = __shfl_down(bi, off, 64);
        const float ol = __shfl_down(bl, off, 64);
        if (ov > bv || (ov == bv && oi < bi)) { bv = ov; bi = oi; bl = ol; }
    }
    const int   label = __shfl(bi, 0, 64);
    const float x1    = __shfl(bl, 0, 64);

    // ---- hinge sum from registers ----
    // j==0: neg term, margin 1.0 (NEG_MARGIN=1). j==label: margin 0, relu(0)=0, harmless.
    const float inv_pos = 1.0f / (float)(NC - 1);
    float sum = 0.0f;
    #pragma unroll
    for (int k = 0; k < KPL; ++k) {
        const int idx = lane + 64 * k;
        if (idx < NV4) {
            const int base = idx * 4;
            const float lvals[4] = {lv[k].x, lv[k].y, lv[k].z, lv[k].w};
            #pragma unroll
            for (int e = 0; e < 4; ++e) {
                const int j = base + e;
                const float margin = (j == 0) ? 1.0f
                                              : fabsf((float)(label - j)) * inv_pos;
                sum += fmaxf(lvals[e] - x1 + margin, 0.0f);
            }
        }
    }
    #pragma unroll
    for (int off = 32; off > 0; off >>= 1)
        sum += __shfl_down(sum, off, 64);

    if (lane == 0)
        partial[row] = (label != 0) ? sum * (1.0f / (float)NB) : 0.0f;
}

// Sum 16384 partials -> out[0]. One block, 256 threads, float4 loads.
__global__ __launch_bounds__(256) void reduce_partials_kernel(
        const float* __restrict__ partial,
        float* __restrict__ out) {
    const int t    = threadIdx.x;
    const int wave = t >> 6;
    const int lane = t & 63;

    float sum = 0.0f;
    const float4* p4 = (const float4*)partial;
    #pragma unroll
    for (int i = 0; i < 16; ++i) {
        float4 v = p4[t + i * 256];
        sum += (v.x + v.y) + (v.z + v.w);
    }
    #pragma unroll
    for (int off = 32; off > 0; off >>= 1)
        sum += __shfl_down(sum, off, 64);

    __shared__ float s_sum[4];
    if (lane == 0) s_sum[wave] = sum;
    __syncthreads();
    if (t == 0)
        out[0] = s_sum[0] + s_sum[1] + s_sum[2] + s_sum[3];
}

extern "C" void kernel_launch(void* const* d_in, const int* in_sizes, int n_in,
                              void* d_out, int out_size, void* d_ws, size_t ws_size,
                              hipStream_t stream) {
    const float* logits = (const float*)d_in[0];
    const float* target = (const float*)d_in[1];
    float* out     = (float*)d_out;
    float* partial = (float*)d_ws;   // NB floats = 64 KB scratch

    ranking_loss_kernel<<<NB / 4, 256, 0, stream>>>(logits, target, partial);
    reduce_partials_kernel<<<1, 256, 0, stream>>>(partial, out);
}

// Round 2
// 142.015 us; speedup vs baseline: 1.0012x; 1.0012x over previous
//
#include <hip/hip_runtime.h>
#include <stdint.h>

#define NB 16384     // rows (B)
#define NC 1000      // classes (C)
#define NV4 250      // float4 per row
#define RPW 2        // rows per wave
#define WPB 4        // waves per block (256 threads)

// Opaque keep: after this, values live in VGPRs and cannot be rematerialized
// by re-loading from memory (asm may have modified them).
#define KEEP4(v) asm volatile("" : "+v"((v).x), "+v"((v).y), "+v"((v).z), "+v"((v).w))

// One wave handles RPW rows; all 16 float4 loads issued up front, lv pinned
// in registers across the argmax so phase 2 never touches memory again.
// Argmax is a single u64-key max: key = (bits(target) << 32) | ~j.
// (targets are uniform[0,1) => non-negative => IEEE bits order == value order;
//  tie on value => larger ~j == smaller j == first occurrence, matching argmax.)
__global__ __launch_bounds__(256) void ranking_loss_kernel(
        const float* __restrict__ logits,
        const float* __restrict__ target,
        float* __restrict__ partial) {
    const int wave = threadIdx.x >> 6;
    const int lane = threadIdx.x & 63;
    const int row0 = (blockIdx.x * WPB + wave) * RPW;

    // ---- issue ALL global loads up front (16 dwordx4, no guards) ----
    float4 tv[RPW][4], lv[RPW][4];
    #pragma unroll
    for (int r = 0; r < RPW; ++r) {
        const float4* __restrict__ t4 = (const float4*)(target + (size_t)(row0 + r) * NC);
        const float4* __restrict__ l4 = (const float4*)(logits + (size_t)(row0 + r) * NC);
        #pragma unroll
        for (int k = 0; k < 4; ++k) {
            const int idx  = lane + 64 * k;
            const int cidx = (k == 3) ? min(idx, NV4 - 1) : idx;  // clamp tail lanes
            tv[r][k] = t4[cidx];
            lv[r][k] = l4[cidx];
        }
    }

    // ---- tail fixup (lanes 58..63 at k==3 hold duplicates of element 249) ----
    const bool tail = (lane + 192) >= NV4;
    #pragma unroll
    for (int r = 0; r < RPW; ++r) {
        if (tail) {
            tv[r][3] = make_float4(0.f, 0.f, 0.f, 0.f);          // key never wins
            lv[r][3] = make_float4(-1e30f, -1e30f, -1e30f, -1e30f); // hinge -> 0
        }
    }

    // ---- per-lane argmax scan: single u64 key carries (value, index) ----
    unsigned long long key[RPW];
    float bl[RPW];
    #pragma unroll
    for (int r = 0; r < RPW; ++r) {
        unsigned long long bk = 0ull;
        float b = 0.f;
        #pragma unroll
        for (int k = 0; k < 4; ++k) {
            const float tvals[4] = {tv[r][k].x, tv[r][k].y, tv[r][k].z, tv[r][k].w};
            const float lvals[4] = {lv[r][k].x, lv[r][k].y, lv[r][k].z, lv[r][k].w};
            #pragma unroll
            for (int e = 0; e < 4; ++e) {
                const int j = (lane + 64 * k) * 4 + e;
                const unsigned long long c =
                    ((unsigned long long)__float_as_uint(tvals[e]) << 32)
                    | (unsigned int)(~j);
                if (c > bk) { bk = c; b = lvals[e]; }
            }
        }
        key[r] = bk; bl[r] = b;
    }

    // ---- pin lv live across the reduction (forbid reload) ----
    #pragma unroll
    for (int r = 0; r < RPW; ++r) {
        KEEP4(lv[r][0]); KEEP4(lv[r][1]); KEEP4(lv[r][2]); KEEP4(lv[r][3]);
    }

    // ---- butterfly argmax reduce, both rows interleaved (independent chains) ----
    #pragma unroll
    for (int off = 32; off; off >>= 1) {
        #pragma unroll
        for (int r = 0; r < RPW; ++r) {
            const unsigned long long ok = __shfl_xor(key[r], off, 64);
            const float              ob = __shfl_xor(bl[r], off, 64);
            if (ok > key[r]) { key[r] = ok; bl[r] = ob; }
        }
    }

    // ---- hinge sums from registers; butterfly sum; store ----
    const float inv_pos = 1.0f / (float)(NC - 1);
    #pragma unroll
    for (int r = 0; r < RPW; ++r) {
        const int   label = (int)(~(unsigned int)key[r]);  // low 32 bits = ~j
        const float x1    = bl[r];                          // logit at label, all lanes
        float s0 = 0.f, s1 = 0.f;
        #pragma unroll
        for (int k = 0; k < 4; ++k) {
            const float lvals[4] = {lv[r][k].x, lv[r][k].y, lv[r][k].z, lv[r][k].w};
            #pragma unroll
            for (int e = 0; e < 4; ++e) {
                const int j = (lane + 64 * k) * 4 + e;
                const float dj = fabsf((float)(label - j));
                float m = dj * inv_pos;
                if (k == 0 && e == 0) m = (lane == 0) ? 1.0f : m;  // j==0 neg term
                const float c = fmaxf(lvals[e] - x1 + m, 0.f);
                if (e & 1) s1 += c; else s0 += c;
            }
        }
        float sum = s0 + s1;
        #pragma unroll
        for (int off = 32; off; off >>= 1)
            sum += __shfl_xor(sum, off, 64);
        if (lane == 0)
            partial[row0 + r] = (label != 0) ? sum * (1.0f / (float)NB) : 0.0f;
    }
}

// Sum 16384 partials -> out[0]. One block, 256 threads, float4 loads.
__global__ __launch_bounds__(256) void reduce_partials_kernel(
        const float* __restrict__ partial,
        float* __restrict__ out) {
    const int t    = threadIdx.x;
    const int wave = t >> 6;
    const int lane = t & 63;

    float sum = 0.0f;
    const float4* p4 = (const float4*)partial;
    #pragma unroll
    for (int i = 0; i < 16; ++i) {
        float4 v = p4[t + i * 256];
        sum += (v.x + v.y) + (v.z + v.w);
    }
    #pragma unroll
    for (int off = 32; off > 0; off >>= 1)
        sum += __shfl_down(sum, off, 64);

    __shared__ float s_sum[4];
    if (lane == 0) s_sum[wave] = sum;
    __syncthreads();
    if (t == 0)
        out[0] = s_sum[0] + s_sum[1] + s_sum[2] + s_sum[3];
}

extern "C" void kernel_launch(void* const* d_in, const int* in_sizes, int n_in,
                              void* d_out, int out_size, void* d_ws, size_t ws_size,
                              hipStream_t stream) {
    const float* logits = (const float*)d_in[0];
    const float* target = (const float*)d_in[1];
    float* out     = (float*)d_out;
    float* partial = (float*)d_ws;   // NB floats = 64 KB scratch

    ranking_loss_kernel<<<NB / (WPB * RPW), 256, 0, stream>>>(logits, target, partial);
    reduce_partials_kernel<<<1, 256, 0, stream>>>(partial, out);
}